// Round 18
// baseline (916.809 us; speedup 1.0000x reference)
//
#include <hip/hip_runtime.h>
#include <math.h>
#include <type_traits>

using u16 = unsigned short;
using u32 = unsigned int;

typedef __bf16 bf16x8 __attribute__((ext_vector_type(8)));
typedef float f32x4 __attribute__((ext_vector_type(4)));
typedef float f32x16 __attribute__((ext_vector_type(16)));

// ---------- bf16 helpers ----------
__device__ __forceinline__ float lof(u32 u) { u32 x = u << 16; float f; __builtin_memcpy(&f, &x, 4); return f; }
__device__ __forceinline__ float hif(u32 u) { u32 x = u & 0xffff0000u; float f; __builtin_memcpy(&f, &x, 4); return f; }
__device__ __forceinline__ u16 f2bf(float f) {
  u32 u; __builtin_memcpy(&u, &f, 4);
  u32 r = u + 0x7fffu + ((u >> 16) & 1u);
  return (u16)(r >> 16);
}
__device__ __forceinline__ u32 pack2(float a, float b) { return (u32)f2bf(a) | ((u32)f2bf(b) << 16); }
__device__ __forceinline__ float bf2f(u16 s) { u32 x = ((u32)s) << 16; float f; __builtin_memcpy(&f, &x, 4); return f; }
__device__ __forceinline__ float elem(const u32* arr, int j) { u32 u = arr[j >> 1]; return (j & 1) ? hif(u) : lof(u); }

__device__ __forceinline__ void gload_lds16(const u16* g, u16* l) {
  __builtin_amdgcn_global_load_lds((const __attribute__((address_space(1))) void*)g,
                                   (__attribute__((address_space(3))) void*)l, 16, 0, 0);
}

// cheap GELU: tanh form via HW exp+rcp, |err| <~ 1e-3 absolute.
__device__ __forceinline__ float gelu_f(float x) {
  float x3 = x * x * x;
  float u = fmaf(x3, 0.07135481283f, 1.5957691216f * x);
  float e = __expf(u);
  float r = __builtin_amdgcn_rcpf(e + 1.0f);
  return x * e * r;
}

// ---------- problem constants ----------
#define NTOK 65536      // B*C*P = 8*64*128

// bf16 weight elem offsets inside O_WB
#define WB_PA   0         // proj_attn_w 512x512
#define WB_PF   262144    // proj_ffn_w  512x512 (also packed into W2F)
#define WB_QS   524288    // qkv_s_w*ln1w 768x256
#define WB_QT   720896    // qkv_t_w*ln1w 768x256
#define WB_OS   917504    // out_s_w     256x256
#define WB_OT   983040    // out_t_w     256x256
#define WB_W1   1048576   // w1*ln2w     2048x512
#define WB_W2F  2097152   // [w2 | proj_ffn_w] 512x2560
#define WB_TOT  3407872

// uc float offsets
#define UC_US 0
#define UC_CS 768
#define UC_UT 1536
#define UC_CT 2304
#define UC_U1 3072
#define UC_C1 5120
#define UC_BC 7168

// ws layout (bytes)
constexpr size_t O_WB  = 0;
constexpr size_t O_TAB = 6815744;
constexpr size_t O_ST1 = 6864896;
constexpr size_t O_ST2 = 7389184;
constexpr size_t O_UC  = 7913472;
constexpr size_t O_X   = 7944192;
constexpr size_t O_HB  = O_X + (size_t)NTOK * 512 * 2;

// ---------- weight conversion (with LN folds + fused w2) ----------
__global__ __launch_bounds__(256) void convert_weights_kernel(
    const float* __restrict__ pa, const float* __restrict__ pf,
    const float* __restrict__ qs, const float* __restrict__ qt,
    const float* __restrict__ os_, const float* __restrict__ ot,
    const float* __restrict__ w1, const float* __restrict__ w2,
    const float* __restrict__ ln1w, const float* __restrict__ ln2w,
    u16* __restrict__ dst)
{
  int i = blockIdx.x * 256 + threadIdx.x;
  if (i >= WB_TOT) return;
  float v;
  if (i < 262144)       { v = pa[i]; }
  else if (i < 524288)  { v = pf[i - 262144]; }
  else if (i < 720896)  { int l = i - 524288;  v = qs[l] * ln1w[l & 255]; }
  else if (i < 917504)  { int l = i - 720896;  v = qt[l] * ln1w[256 + (l & 255)]; }
  else if (i < 983040)  { v = os_[i - 917504]; }
  else if (i < 1048576) { v = ot[i - 983040]; }
  else if (i < 2097152) { int l = i - 1048576; v = w1[l] * ln2w[l & 511]; }
  else {
    int l = i - 2097152; int row = l / 2560, col = l - row * 2560;
    v = (col < 2048) ? w2[row * 2048 + col] : pf[row * 512 + (col - 2048)];
  }
  dst[i] = f2bf(v);
}

// ---------- u/c correction vectors + combined bias (wave-parallel) ----------
__global__ __launch_bounds__(256) void ucvec_kernel(
    const float* __restrict__ qs, const float* __restrict__ qt, const float* __restrict__ w1,
    const float* __restrict__ ln1w, const float* __restrict__ ln1b,
    const float* __restrict__ ln2w, const float* __restrict__ ln2b,
    const float* __restrict__ b2, const float* __restrict__ pfb,
    float* __restrict__ uc)
{
  const int j = blockIdx.x * 4 + (threadIdx.x >> 6);
  const int l = threadIdx.x & 63;
  float u = 0.f, c = 0.f;
  if (j < 768) {
#pragma unroll
    for (int q = 0; q < 4; q++) {
      int k = l * 4 + q;
      float w = qs[j * 256 + k];
      u += ln1w[k] * w; c += ln1b[k] * w;
    }
  } else if (j < 1536) {
    int jj = j - 768;
#pragma unroll
    for (int q = 0; q < 4; q++) {
      int k = l * 4 + q;
      float w = qt[jj * 256 + k];
      u += ln1w[256 + k] * w; c += ln1b[256 + k] * w;
    }
  } else if (j < 3584) {
    int jj = j - 1536;
#pragma unroll
    for (int q = 0; q < 8; q++) {
      int k = l * 8 + q;
      float w = w1[jj * 512 + k];
      u += ln2w[k] * w; c += ln2b[k] * w;
    }
  } else if (j < 4096) {
    if (l == 0) { int jj = j - 3584; uc[UC_BC + jj] = b2[jj] + pfb[jj]; }
    return;
  } else return;
#pragma unroll
  for (int o = 32; o > 0; o >>= 1) { u += __shfl_xor(u, o); c += __shfl_xor(c, o); }
  if (l == 0) {
    if (j < 768)       { uc[UC_US + j] = u;          uc[UC_CS + j] = c; }
    else if (j < 1536) { uc[UC_UT + (j - 768)] = u;  uc[UC_CT + (j - 768)] = c; }
    else               { uc[UC_U1 + (j - 1536)] = u; uc[UC_C1 + (j - 1536)] = c; }
  }
}

// ---------- rope tables ----------
__global__ __launch_bounds__(256) void rope_tables_kernel(const float* __restrict__ coords, float* __restrict__ tab)
{
  __shared__ float cs[192];
  __shared__ float mean3[3];
  __shared__ float rmax;
  int t = threadIdx.x;
  if (t < 192) cs[t] = coords[t];
  __syncthreads();
  if (t < 3) { float s = 0.f; for (int i = 0; i < 64; i++) s += cs[i * 3 + t]; mean3[t] = s * (1.0f / 64.0f); }
  __syncthreads();
  if (t < 192) cs[t] -= mean3[t % 3];
  __syncthreads();
  if (t == 0) {
    float mx = 0.f;
    for (int i = 0; i < 64; i++) {
      float x = cs[i * 3], y = cs[i * 3 + 1], z = cs[i * 3 + 2];
      mx = fmaxf(mx, sqrtf(x * x + y * y + z * z));
    }
    rmax = fmaxf(mx, 1e-6f);
  }
  __syncthreads();
  float inv = 1.0f / rmax;
  for (int e = t; e < 2048; e += 256) {
    int c = e >> 5, j = e & 31;
    float freq = 1.0f / powf(10000.0f, (float)j * (1.0f / 32.0f));
    float th = 6.283185307179586f * (cs[c * 3 + (j % 3)] * inv) * freq;
    tab[e] = cosf(th); tab[2048 + e] = sinf(th);
  }
  for (int e = t; e < 4096; e += 256) {
    int p = e >> 5, j = e & 31;
    float freq = 1.0f / powf(10000.0f, (float)j * (1.0f / 32.0f));
    float th = (float)p * freq;
    tab[4096 + e] = cosf(th); tab[8192 + e] = sinf(th);
  }
}

// ---------- LN stats (mean, rstd) per token; optional bf16 cast of src ----------
__global__ __launch_bounds__(256) void ln_stats_f32_kernel(
    const float* __restrict__ xin, float2* __restrict__ st, u16* __restrict__ srcb)
{
  const int tok = blockIdx.x * 4 + (threadIdx.x >> 6);
  const int lane = threadIdx.x & 63;
  const float* row = xin + (size_t)tok * 512 + lane * 8;
  float4 v0 = ((const float4*)row)[0];
  float4 v1 = ((const float4*)row)[1];
  float v[8] = {v0.x, v0.y, v0.z, v0.w, v1.x, v1.y, v1.z, v1.w};
  float s = 0.f, ss = 0.f;
#pragma unroll
  for (int j = 0; j < 8; j++) { s += v[j]; ss += v[j] * v[j]; }
#pragma unroll
  for (int o = 32; o > 0; o >>= 1) { s += __shfl_xor(s, o); ss += __shfl_xor(ss, o); }
  if (lane == 0) {
    float mean = s * (1.0f / 512.0f);
    float rstd = rsqrtf(ss * (1.0f / 512.0f) - mean * mean + 1e-5f);
    st[tok] = make_float2(mean, rstd);
  }
  if (srcb) {
    uint4 o; u32* op = (u32*)&o;
#pragma unroll
    for (int d = 0; d < 4; d++) op[d] = pack2(v[2 * d], v[2 * d + 1]);
    *(uint4*)(srcb + (size_t)tok * 512 + lane * 8) = o;
  }
}

__global__ __launch_bounds__(256) void ln_stats_bf16_kernel(const u16* __restrict__ xin, float2* __restrict__ st)
{
  const int tok = blockIdx.x * 4 + (threadIdx.x >> 6);
  const int lane = threadIdx.x & 63;
  uint4 u = ((const uint4*)(xin + (size_t)tok * 512))[lane];
  u32 uu[4] = {u.x, u.y, u.z, u.w};
  float s = 0.f, ss = 0.f;
#pragma unroll
  for (int d = 0; d < 4; d++) {
    float a = lof(uu[d]), b = hif(uu[d]);
    s += a + b; ss += a * a + b * b;
  }
#pragma unroll
  for (int o = 32; o > 0; o >>= 1) { s += __shfl_xor(s, o); ss += __shfl_xor(ss, o); }
  if (lane == 0) {
    float mean = s * (1.0f / 512.0f);
    float rstd = rsqrtf(ss * (1.0f / 512.0f) - mean * mean + 1e-5f);
    st[tok] = make_float2(mean, rstd);
  }
}

// ---------- 128x128-tile, BK=32, 4-buffer, 2-tile WINDOW pipeline (small GEMMs) ----------
// EMODE: 0 = +bias; 2 = +bias+RMW; 3 = affine(stats,u,c)+bias
template<int EMODE, typename OutT>
__global__ __launch_bounds__(256) void gemm128w_kernel(
    const u16* __restrict__ A16, int lda,
    const u16* __restrict__ Wt, int ldw,
    OutT* __restrict__ C, int ldc,
    const float* __restrict__ bias,
    const float2* __restrict__ stats,
    const float* __restrict__ uvec, const float* __restrict__ cvec,
    int K)
{
  __shared__ u16 As[4][128 * 32];
  __shared__ u16 Bs[4][128 * 32];
  const int t = threadIdx.x;
  const int lane = t & 63, wid = t >> 6;
  const int wm = wid >> 1, wn = wid & 1;
  const int l15 = lane & 15, l4 = lane >> 4;
  const int chs = (t & 3) ^ ((t >> 3) & 3);

  const int ntn = gridDim.x;
  const int nwg = ntn * gridDim.y;
  int flat = blockIdx.y * ntn + blockIdx.x;
  int q = nwg >> 3, rmd = nwg & 7, xcd = flat & 7, idx = flat >> 3;
  int wg = (xcd < rmd ? xcd * (q + 1) : rmd * (q + 1) + (xcd - rmd) * q) + idx;
  const int m0 = (wg / ntn) * 128, n0 = (wg % ntn) * 128;

  f32x4 acc[4][4] = {};
  const int r0 = t >> 2;
  const size_t arow0 = (size_t)(m0 + r0);
  const u16* Wp = Wt + (size_t)(n0 + r0) * ldw + chs * 8;
  const size_t wstep = (size_t)64 * ldw;
  const int nt = K / 32;   // even for all K used (256, 512)

  auto stage = [&](int ti, int buf) {
    const int kk = ti * 32;
    const u16* pa = A16 + arow0 * lda + kk + chs * 8;
    const size_t rstep = (size_t)64 * lda;
    gload_lds16(pa, &As[buf][t * 8]);
    gload_lds16(pa + rstep, &As[buf][t * 8 + 2048]);
    gload_lds16(Wp + kk, &Bs[buf][t * 8]);
    gload_lds16(Wp + wstep + kk, &Bs[buf][t * 8 + 2048]);
  };

  stage(0, 0);
  stage(1, 1);
  const int pco = (l4 ^ ((l15 >> 1) & 3)) * 8;
  for (int p = 0; p < nt; p += 2) {
    __builtin_amdgcn_sched_barrier(0);
    asm volatile("s_waitcnt vmcnt(0)" ::: "memory");
    __builtin_amdgcn_sched_barrier(0);
    __builtin_amdgcn_s_barrier();
    __builtin_amdgcn_sched_barrier(0);
    if (p + 2 < nt) stage(p + 2, (p + 2) & 3);
    if (p + 3 < nt) stage(p + 3, (p + 3) & 3);
#pragma unroll
    for (int s = 0; s < 2; s++) {
      const u16* Ab = &As[(p + s) & 3][0];
      const u16* Bb = &Bs[(p + s) & 3][0];
      bf16x8 af[4], bfr[4];
#pragma unroll
      for (int i = 0; i < 4; i++)
        af[i] = *(const bf16x8*)(Ab + (wm * 64 + i * 16 + l15) * 32 + pco);
#pragma unroll
      for (int j = 0; j < 4; j++)
        bfr[j] = *(const bf16x8*)(Bb + (wn * 64 + j * 16 + l15) * 32 + pco);
#pragma unroll
      for (int i = 0; i < 4; i++)
#pragma unroll
        for (int j = 0; j < 4; j++)
          acc[i][j] = __builtin_amdgcn_mfma_f32_16x16x32_bf16(af[i], bfr[j], acc[i][j], 0, 0, 0);
    }
    __builtin_amdgcn_sched_barrier(0);
  }

#pragma unroll
  for (int i = 0; i < 4; i++) {
    const int row = m0 + wm * 64 + i * 16 + l4 * 4;
#pragma unroll
    for (int j = 0; j < 4; j++) {
      const int col = n0 + wn * 64 + j * 16 + l15;
      const float bv = bias[col];
#pragma unroll
      for (int rr = 0; rr < 4; rr++) {
        float v = acc[i][j][rr];
        if constexpr (EMODE == 3) {
          float2 s = stats[row + rr];
          v = s.y * v - s.x * s.y * uvec[col] + cvec[col] + bv;
        } else {
          v += bv;
        }
        const size_t idxc = (size_t)(row + rr) * ldc + col;
        if constexpr (std::is_same<OutT, u16>::value) {
          if constexpr (EMODE == 2) v += bf2f(C[idxc]);
          C[idxc] = f2bf(v);
        } else {
          if constexpr (EMODE == 2) v += C[idxc];
          C[idxc] = v;
        }
      }
    }
  }
}

// ---------- 256x256-tile, BK=32, 4-buffer, 2-tile WINDOW pipeline, 32x32 MFMA (FFN) ----------
// Same window schedule as r15/r17 best; MFMA shape 32x32x16 (16 instr/tile vs 32 at
// 16x16: ~15% fewer matrix-pipe cycles per m119; same 12 ds_read_b128/tile).
// Fragment layout (m74/m101 verified): A/B lane l -> row/col = l&31, k = (l>>5)*8 + j;
// C/D: col = l&31, row = (r&3) + 8*(r>>2) + 4*(l>>5), r in [0,16).
// Swizzled read chunk: ((ks*2)|l5) ^ ((l31>>1)&3) -> 2-way/quarter-phase (free).
// AMODE: 0 = single bf16 A; 4 = dual A (k<2048 -> A16 else A2; boundary tile-aligned)
// EMODE: 0 = +bias; 4 = gelu(affine(stats,u,c)+bias)
template<int AMODE, int EMODE, typename OutT>
__global__ __launch_bounds__(512, 2) void gemm2w_kernel(
    const u16* __restrict__ A16, int lda,
    const u16* __restrict__ A2, int lda2,
    const u16* __restrict__ Wt, int ldw,
    OutT* __restrict__ C, int ldc,
    const float* __restrict__ bias,
    const float2* __restrict__ stats,
    const float* __restrict__ uvec, const float* __restrict__ cvec,
    int K)
{
  __shared__ u16 As[4][256 * 32];
  __shared__ u16 Bs[4][256 * 32];
  const int t = threadIdx.x;
  const int lane = t & 63, wid = t >> 6;
  const int wm = wid >> 2, wn = wid & 3;     // 2M x 4N -> 128x64 per wave
  const int l31 = lane & 31, l5 = lane >> 5;
  const int r0 = t >> 2;
  const int chs = (t & 3) ^ ((t >> 3) & 3);

  const int ntn = gridDim.x;
  const int nwg = ntn * gridDim.y;
  int flat = blockIdx.y * ntn + blockIdx.x;
  int q = nwg >> 3, rmd = nwg & 7, xcd = flat & 7, idx = flat >> 3;
  int wg = (xcd < rmd ? xcd * (q + 1) : rmd * (q + 1) + (xcd - rmd) * q) + idx;
  const int m0 = (wg / ntn) * 256, n0 = (wg % ntn) * 256;

  f32x16 acc[4][2] = {};   // 4 M-tiles x 2 N-tiles of 32x32 (128x64 per wave)

  const size_t arow0 = (size_t)(m0 + r0);
  const u16* Wp = Wt + (size_t)(n0 + r0) * ldw + chs * 8;
  const size_t wstep = (size_t)128 * ldw;
  const int nt = K >> 5;   // even for all our K (512, 2560)

  auto stage = [&](int ti, int buf) {
    const int kk = ti << 5;
    const int cbk = kk + chs * 8;
    const u16* pa; size_t rstep;
    if constexpr (AMODE == 4) {
      if (kk < 2048) { pa = A16 + arow0 * lda + cbk;          rstep = (size_t)128 * lda; }
      else           { pa = A2 + arow0 * lda2 + (cbk - 2048); rstep = (size_t)128 * lda2; }
    } else {
      pa = A16 + arow0 * lda + cbk; rstep = (size_t)128 * lda;
    }
    gload_lds16(pa,         &As[buf][t * 8]);
    gload_lds16(pa + rstep, &As[buf][t * 8 + 4096]);
    gload_lds16(Wp + kk,          &Bs[buf][t * 8]);
    gload_lds16(Wp + wstep + kk,  &Bs[buf][t * 8 + 4096]);
  };

  stage(0, 0);
  stage(1, 1);
  const int swz = (l31 >> 1) & 3;
  const int xc0 = ((l5 ^ swz) * 8);            // ks=0: chunk (0|l5)^swz
  const int xc1 = (((2 | l5) ^ swz) * 8);      // ks=1: chunk (2|l5)^swz
  for (int p = 0; p < nt; p += 2) {
    __builtin_amdgcn_sched_barrier(0);
    asm volatile("s_waitcnt vmcnt(0)" ::: "memory");
    __builtin_amdgcn_sched_barrier(0);
    __builtin_amdgcn_s_barrier();
    __builtin_amdgcn_sched_barrier(0);
    if (p + 2 < nt) stage(p + 2, (p + 2) & 3);
    if (p + 3 < nt) stage(p + 3, (p + 3) & 3);
#pragma unroll
    for (int s = 0; s < 2; s++) {
      const u16* Ab = &As[(p + s) & 3][0];
      const u16* Bb = &Bs[(p + s) & 3][0];
#pragma unroll
      for (int ks = 0; ks < 2; ks++) {
        const int xc = ks ? xc1 : xc0;
        bf16x8 af[4], bfr[2];
#pragma unroll
        for (int i = 0; i < 4; i++)
          af[i] = *(const bf16x8*)(Ab + (wm * 128 + i * 32 + l31) * 32 + xc);
#pragma unroll
        for (int j = 0; j < 2; j++)
          bfr[j] = *(const bf16x8*)(Bb + (wn * 64 + j * 32 + l31) * 32 + xc);
        __builtin_amdgcn_s_setprio(1);
#pragma unroll
        for (int i = 0; i < 4; i++)
#pragma unroll
          for (int j = 0; j < 2; j++)
            acc[i][j] = __builtin_amdgcn_mfma_f32_32x32x16_bf16(af[i], bfr[j], acc[i][j], 0, 0, 0);
        __builtin_amdgcn_s_setprio(0);
      }
    }
    __builtin_amdgcn_sched_barrier(0);
  }

#pragma unroll
  for (int i = 0; i < 4; i++) {
#pragma unroll
    for (int j = 0; j < 2; j++) {
      const int col = n0 + wn * 64 + j * 32 + l31;
      const float bv = bias[col];
      float uv = 0.f, cv = 0.f;
      if constexpr (EMODE == 4) { uv = uvec[col]; cv = cvec[col]; }
#pragma unroll
      for (int r = 0; r < 16; r++) {
        const int row = m0 + wm * 128 + i * 32 + (r & 3) + ((r >> 2) << 3) + (l5 << 2);
        float v = acc[i][j][r];
        if constexpr (EMODE == 4) {
          float2 s = stats[row];
          v = s.y * v - s.x * s.y * uv + cv + bv;
          v = gelu_f(v);
        } else {
          v += bv;
        }
        const size_t idxc = (size_t)row * ldc + col;
        if constexpr (std::is_same<OutT, u16>::value) C[idxc] = f2bf(v);
        else C[idxc] = v;
      }
    }
  }
}

// ---------- legacy 128x128 kernel (f32 reg-staged A; fallback when ws too small) ----------
template<int EMODE, typename OutT>
__global__ __launch_bounds__(256) void gemm_f32a_kernel(
    const float* __restrict__ A32, int lda,
    const u16* __restrict__ Wt, int ldw,
    OutT* __restrict__ C, int ldc,
    const float* __restrict__ bias,
    const float2* __restrict__ stats,
    const float* __restrict__ uvec, const float* __restrict__ cvec,
    int K)
{
  const int t = threadIdx.x;
  const int lane = t & 63, wid = t >> 6;
  const int wm = wid >> 1, wn = wid & 1;
  const int l15 = lane & 15, l4 = lane >> 4;
  const int r0 = t >> 2;
  const int ntn = gridDim.x;
  const int nwg = ntn * gridDim.y;
  int flat = blockIdx.y * ntn + blockIdx.x;
  int q = nwg >> 3, rmd = nwg & 7, xcd = flat & 7, idx = flat >> 3;
  int wg = (xcd < rmd ? xcd * (q + 1) : rmd * (q + 1) + (xcd - rmd) * q) + idx;
  const int m0 = (wg / ntn) * 128, n0 = (wg % ntn) * 128;
  f32x4 acc[4][4] = {};
  const size_t arow0 = (size_t)(m0 + r0);
  const int ch = t & 3;
  const u16* Wp = Wt + (size_t)(n0 + r0) * ldw + ch * 8;
  const size_t wstep = (size_t)64 * ldw;
  __shared__ u16 As[128 * 40];
  __shared__ u16 Bs[128 * 32];
  for (int k0 = 0; k0 < K; k0 += 32) {
    const int cbx = k0 + ch * 8;
    uint4 a0, a1;
    float f0[8], f1[8];
    float4 x0 = *(const float4*)(A32 + arow0 * lda + cbx);
    float4 x1 = *(const float4*)(A32 + arow0 * lda + cbx + 4);
    float4 y0 = *(const float4*)(A32 + (arow0 + 64) * lda + cbx);
    float4 y1 = *(const float4*)(A32 + (arow0 + 64) * lda + cbx + 4);
    f0[0]=x0.x; f0[1]=x0.y; f0[2]=x0.z; f0[3]=x0.w; f0[4]=x1.x; f0[5]=x1.y; f0[6]=x1.z; f0[7]=x1.w;
    f1[0]=y0.x; f1[1]=y0.y; f1[2]=y0.z; f1[3]=y0.w; f1[4]=y1.x; f1[5]=y1.y; f1[6]=y1.z; f1[7]=y1.w;
    u32* p0 = (u32*)&a0; u32* p1 = (u32*)&a1;
#pragma unroll
    for (int d = 0; d < 4; d++) { p0[d] = pack2(f0[2*d], f0[2*d+1]); p1[d] = pack2(f1[2*d], f1[2*d+1]); }
    __syncthreads();
    gload_lds16(Wp + k0, Bs + t * 8);
    gload_lds16(Wp + wstep + k0, Bs + t * 8 + 2048);
    *(uint4*)(As + r0 * 40 + ch * 8) = a0;
    *(uint4*)(As + (r0 + 64) * 40 + ch * 8) = a1;
    __syncthreads();
    bf16x8 af[4], bfr[4];
#pragma unroll
    for (int i = 0; i < 4; i++)
      af[i] = *(const bf16x8*)(As + (wm * 64 + i * 16 + l15) * 40 + l4 * 8);
#pragma unroll
    for (int j = 0; j < 4; j++)
      bfr[j] = *(const bf16x8*)(Bs + (wn * 64 + j * 16 + l15) * 32 + l4 * 8);
#pragma unroll
    for (int i = 0; i < 4; i++)
#pragma unroll
      for (int j = 0; j < 4; j++)
        acc[i][j] = __builtin_amdgcn_mfma_f32_16x16x32_bf16(af[i], bfr[j], acc[i][j], 0, 0, 0);
  }
#pragma unroll
  for (int i = 0; i < 4; i++) {
    const int row = m0 + wm * 64 + i * 16 + l4 * 4;
#pragma unroll
    for (int j = 0; j < 4; j++) {
      const int col = n0 + wn * 64 + j * 16 + l15;
      const float bv = bias[col];
#pragma unroll
      for (int rr = 0; rr < 4; rr++) {
        float v = acc[i][j][rr];
        if constexpr (EMODE == 3) {
          float2 s = stats[row + rr];
          v = s.y * v - s.x * s.y * uvec[col] + cvec[col] + bv;
        } else {
          v += bv;
        }
        const size_t idxc = (size_t)(row + rr) * ldc + col;
        if constexpr (std::is_same<OutT, u16>::value) C[idxc] = f2bf(v);
        else C[idxc] = v;
      }
    }
  }
}

// ---------- MFMA fused attention: rope + QK^T + softmax + PV ----------
template<int L>
__global__ __launch_bounds__(256) void attn_mfma_kernel(
    const u16* __restrict__ qkv,   // [NTOK][768]
    u16* __restrict__ aout,        // [NTOK][256]
    const float* __restrict__ tab)
{
  constexpr int KP = 72;
  constexpr int PP = L + 8;
  constexpr int VP = L + 8;
  constexpr int NI = L / 64;
  constexpr int NJ = L / 16;
  constexpr int NK = L / 32;
  __shared__ u16 Ks[L * KP];
  __shared__ u16 Vt[64 * VP];
  __shared__ u16 Ps[L * PP];

  const int t = threadIdx.x;
  const int lane = t & 63;
  const int w = t >> 6;
  const int l15 = lane & 15, l4 = lane >> 4;
  const int sq = blockIdx.x, h = blockIdx.y;

  long base; int tstride; const float *ct, *st;
  if constexpr (L == 64) { base = (long)(sq >> 7) * 8192 + (sq & 127); tstride = 128; ct = tab;        st = tab + 2048; }
  else                   { base = (long)sq * 128;                      tstride = 1;   ct = tab + 4096; st = tab + 8192; }

  {
    const int tok = t >> 1, hh = t & 1;
    if (tok < L) {
      const size_t rb = (size_t)(base + (long)tok * tstride) * 768 + h * 64;
      u32 ku[32];
#pragma unroll
      for (int i = 0; i < 8; i++) ((uint4*)ku)[i] = ((const uint4*)(qkv + rb + 256))[i];
      const float* cc = ct + tok * 32;
      const float* ss = st + tok * 32;
      u32* kd = (u32*)(Ks + tok * KP + hh * 32);
#pragma unroll
      for (int jj = 0; jj < 16; jj++) {
        float c0 = cc[2*jj], s0 = ss[2*jj], c1 = cc[2*jj+1], s1 = ss[2*jj+1];
        float a0 = elem(ku, 2*jj),     b0 = elem(ku, 2*jj+32);
        float a1 = elem(ku, 2*jj+1),   b1 = elem(ku, 2*jj+33);
        float r0v = hh ? (a0*s0 + b0*c0) : (a0*c0 - b0*s0);
        float r1v = hh ? (a1*s1 + b1*c1) : (a1*c1 - b1*s1);
        kd[jj] = pack2(r0v, r1v);
      }
      u32 vu[16];
#pragma unroll
      for (int i = 0; i < 4; i++) ((uint4*)vu)[i] = ((const uint4*)(qkv + rb + 512 + hh * 32))[i];
#pragma unroll
      for (int j = 0; j < 32; j++)
        Vt[(hh * 32 + j) * VP + tok] = (u16)(vu[j >> 1] >> ((j & 1) * 16));
    }
  }

  bf16x8 aq[NI][2];
#pragma unroll
  for (int i = 0; i < NI; i++) {
    const int row = w * (16 * NI) + i * 16 + l15;
    const u16* qr = qkv + (size_t)(base + (long)row * tstride) * 768 + h * 64;
    uint4 ua = *(const uint4*)(qr + l4 * 8);
    uint4 ub = *(const uint4*)(qr + 32 + l4 * 8);
    u32 au[4] = {ua.x, ua.y, ua.z, ua.w};
    u32 bu[4] = {ub.x, ub.y, ub.z, ub.w};
    const float* cc = ct + row * 32 + l4 * 8;
    const float* ss = st + row * 32 + l4 * 8;
    u32 q0[4], q1[4];
#pragma unroll
    for (int d = 0; d < 4; d++) {
      float a0 = lof(au[d]), a1 = hif(au[d]);
      float b0 = lof(bu[d]), b1 = hif(bu[d]);
      float c0 = cc[2*d], c1 = cc[2*d+1], s0 = ss[2*d], s1 = ss[2*d+1];
      q0[d] = pack2(a0*c0 - b0*s0, a1*c1 - b1*s1);
      q1[d] = pack2(a0*s0 + b0*c0, a1*s1 + b1*c1);
    }
    __builtin_memcpy(&aq[i][0], q0, 16);
    __builtin_memcpy(&aq[i][1], q1, 16);
  }
  __syncthreads();

  f32x4 acc[NI][NJ] = {};
#pragma unroll
  for (int j = 0; j < NJ; j++) {
#pragma unroll
    for (int kk = 0; kk < 2; kk++) {
      bf16x8 bk = *(const bf16x8*)(Ks + (j * 16 + l15) * KP + kk * 32 + l4 * 8);
#pragma unroll
      for (int i = 0; i < NI; i++)
        acc[i][j] = __builtin_amdgcn_mfma_f32_16x16x32_bf16(aq[i][kk], bk, acc[i][j], 0, 0, 0);
    }
  }

  float inv_[NI][4];
#pragma unroll
  for (int i = 0; i < NI; i++) {
#pragma unroll
    for (int rr = 0; rr < 4; rr++) {
      float m = acc[i][0][rr];
#pragma unroll
      for (int j = 1; j < NJ; j++) m = fmaxf(m, acc[i][j][rr]);
      m = fmaxf(m, __shfl_xor(m, 1)); m = fmaxf(m, __shfl_xor(m, 2));
      m = fmaxf(m, __shfl_xor(m, 4)); m = fmaxf(m, __shfl_xor(m, 8));
      m *= 0.125f;
      const int qrow = w * (16 * NI) + i * 16 + l4 * 4 + rr;
      float sm = 0.f;
#pragma unroll
      for (int j = 0; j < NJ; j++) {
        float e = __expf(acc[i][j][rr] * 0.125f - m);
        sm += e;
        Ps[qrow * PP + j * 16 + l15] = f2bf(e);
      }
      sm += __shfl_xor(sm, 1); sm += __shfl_xor(sm, 2);
      sm += __shfl_xor(sm, 4); sm += __shfl_xor(sm, 8);
      inv_[i][rr] = 1.0f / sm;
    }
  }

  f32x4 o[NI][4] = {};
#pragma unroll
  for (int kk = 0; kk < NK; kk++) {
    bf16x8 pa[NI];
#pragma unroll
    for (int i = 0; i < NI; i++)
      pa[i] = *(const bf16x8*)(Ps + (w * (16 * NI) + i * 16 + l15) * PP + kk * 32 + l4 * 8);
#pragma unroll
    for (int jn = 0; jn < 4; jn++) {
      bf16x8 bv = *(const bf16x8*)(Vt + (jn * 16 + l15) * VP + kk * 32 + l4 * 8);
#pragma unroll
      for (int i = 0; i < NI; i++)
        o[i][jn] = __builtin_amdgcn_mfma_f32_16x16x32_bf16(pa[i], bv, o[i][jn], 0, 0, 0);
    }
  }

#pragma unroll
  for (int i = 0; i < NI; i++) {
#pragma unroll
    for (int rr = 0; rr < 4; rr++) {
      const int qrow = w * (16 * NI) + i * 16 + l4 * 4 + rr;
      u16* op = aout + (size_t)(base + (long)qrow * tstride) * 256 + h * 64;
      const float iv = inv_[i][rr];
#pragma unroll
      for (int jn = 0; jn < 4; jn++)
        op[jn * 16 + l15] = f2bf(o[i][jn][rr] * iv);
    }
  }
}

// ---------- launch ----------
extern "C" void kernel_launch(void* const* d_in, const int* in_sizes, int n_in,
                              void* d_out, int out_size, void* d_ws, size_t ws_size,
                              hipStream_t stream) {
  const float* src         = (const float*)d_in[0];
  const float* coords      = (const float*)d_in[1];
  const float* proj_attn_w = (const float*)d_in[4];
  const float* proj_attn_b = (const float*)d_in[5];
  const float* proj_ffn_w  = (const float*)d_in[8];
  const float* proj_ffn_b  = (const float*)d_in[9];
  const float* ln1_w = (const float*)d_in[10];
  const float* ln1_b = (const float*)d_in[11];
  const float* ln2_w = (const float*)d_in[12];
  const float* ln2_b = (const float*)d_in[13];
  const float* qkv_s_w = (const float*)d_in[14];
  const float* qkv_s_b = (const float*)d_in[15];
  const float* out_s_w = (const float*)d_in[16];
  const float* out_s_b = (const float*)d_in[17];
  const float* qkv_t_w = (const float*)d_in[18];
  const float* qkv_t_b = (const float*)d_in[19];
  const float* out_t_w = (const float*)d_in[20];
  const float* out_t_b = (const float*)d_in[21];
  const float* w1 = (const float*)d_in[22];
  const float* b1 = (const float*)d_in[23];
  const float* w2 = (const float*)d_in[24];
  const float* b2 = (const float*)d_in[25];
  float* out = (float*)d_out;
  char* ws = (char*)d_ws;

  // FFN chunk: 32768 rows -> hb chunk = 134MB, L3-resident between w1-write and
  // w2-read; w2 grid = 256 blocks (1/CU, full chip).
  const size_t srcb_bytes = (size_t)NTOK * 512 * 2;
  const int tiers[6] = {32768, 16384, 8192, 4096, 2048, 512};
  int crows = 0; bool fast = false;
  for (int i = 0; i < 6; i++) {
    size_t need = O_HB + (size_t)tiers[i] * 2048 * 2 + srcb_bytes;
    if (ws_size >= need) { crows = tiers[i]; fast = true; break; }
  }
  if (!crows) {
    for (int i = 0; i < 6; i++)
      if (ws_size >= O_HB + (size_t)tiers[i] * 2048 * 2) { crows = tiers[i]; break; }
  }
  if (!crows) return;
  size_t o_srcb = O_HB + (size_t)crows * 2048 * 2;

  u16*    wb  = (u16*)(ws + O_WB);
  float*  tab = (float*)(ws + O_TAB);
  float2* st1 = (float2*)(ws + O_ST1);
  float2* st2 = (float2*)(ws + O_ST2);
  float*  uc  = (float*)(ws + O_UC);
  u16*    x   = (u16*)(ws + O_X);
  u16*    hb  = (u16*)(ws + O_HB);
  u16*    srcb = fast ? (u16*)(ws + o_srcb) : nullptr;

  u16* qkvb  = (u16*)d_out;
  u16* aoutb = (u16*)((char*)d_out + (size_t)NTOK * 768 * 2);

  convert_weights_kernel<<<(WB_TOT + 255) / 256, 256, 0, stream>>>(
      proj_attn_w, proj_ffn_w, qkv_s_w, qkv_t_w, out_s_w, out_t_w, w1, w2, ln1_w, ln2_w, wb);
  ucvec_kernel<<<1024, 256, 0, stream>>>(qkv_s_w, qkv_t_w, w1, ln1_w, ln1_b, ln2_w, ln2_b, b2, proj_ffn_b, uc);
  rope_tables_kernel<<<1, 256, 0, stream>>>(coords, tab);
  ln_stats_f32_kernel<<<NTOK / 4, 256, 0, stream>>>(src, st1, srcb);

  // res1 = src @ proj_attn_w^T + b -> x
  if (fast)
    gemm128w_kernel<0, u16><<<dim3(4, 512), 256, 0, stream>>>(srcb, 512, wb + WB_PA, 512, x, 512, proj_attn_b, nullptr, nullptr, nullptr, 512);
  else
    gemm_f32a_kernel<0, u16><<<dim3(4, 512), 256, 0, stream>>>(src, 512, wb + WB_PA, 512, x, 512, proj_attn_b, nullptr, nullptr, nullptr, 512);

  // spatial attention: qkv on raw src with LN folded into weights + affine epilogue
  if (fast)
    gemm128w_kernel<3, u16><<<dim3(6, 512), 256, 0, stream>>>(srcb, 512, wb + WB_QS, 256, qkvb, 768, qkv_s_b, st1, uc + UC_US, uc + UC_CS, 256);
  else
    gemm_f32a_kernel<3, u16><<<dim3(6, 512), 256, 0, stream>>>(src, 512, wb + WB_QS, 256, qkvb, 768, qkv_s_b, st1, uc + UC_US, uc + UC_CS, 256);
  attn_mfma_kernel<64><<<dim3(1024, 4), 256, 0, stream>>>(qkvb, aoutb, tab);
  gemm128w_kernel<2, u16><<<dim3(2, 512), 256, 0, stream>>>(aoutb, 256, wb + WB_OS, 256, x, 512, out_s_b, nullptr, nullptr, nullptr, 256);

  // temporal attention
  if (fast)
    gemm128w_kernel<3, u16><<<dim3(6, 512), 256, 0, stream>>>(srcb + 256, 512, wb + WB_QT, 256, qkvb, 768, qkv_t_b, st1, uc + UC_UT, uc + UC_CT, 256);
  else
    gemm_f32a_kernel<3, u16><<<dim3(6, 512), 256, 0, stream>>>(src + 256, 512, wb + WB_QT, 256, qkvb, 768, qkv_t_b, st1, uc + UC_UT, uc + UC_CT, 256);
  attn_mfma_kernel<128><<<dim3(512, 4), 256, 0, stream>>>(qkvb, aoutb, tab);
  gemm128w_kernel<2, u16><<<dim3(2, 512), 256, 0, stream>>>(aoutb, 256, wb + WB_OT, 256, x + 256, 512, out_t_b, nullptr, nullptr, nullptr, 256);

  // LN2 stats over x (raw x kept; LN2 folded into w1 weights)
  ln_stats_bf16_kernel<<<NTOK / 4, 256, 0, stream>>>(x, st2);

  // FFN chunks: hb = gelu(affine(x @ W1')); out = hb @ w2^T + x @ proj_ffn^T + (b2 + pfb)
  for (int r = 0; r < NTOK; r += crows) {
    gemm2w_kernel<0, 4, u16><<<dim3(8, crows / 256), 512, 0, stream>>>(
        x + (size_t)r * 512, 512, nullptr, 0, wb + WB_W1, 512, hb, 2048, b1, st2 + r, uc + UC_U1, uc + UC_C1, 512);
    gemm2w_kernel<4, 0, float><<<dim3(2, crows / 256), 512, 0, stream>>>(
        hb, 2048, x + (size_t)r * 512, 512, wb + WB_W2F, 2560, out + (size_t)r * 512, 512, uc + UC_BC, nullptr, nullptr, nullptr, 2560);
  }
}

// Round 19
// 903.425 us; speedup vs baseline: 1.0148x; 1.0148x over previous
//
#include <hip/hip_runtime.h>
#include <math.h>
#include <type_traits>

using u16 = unsigned short;
using u32 = unsigned int;

typedef __bf16 bf16x8 __attribute__((ext_vector_type(8)));
typedef float f32x4 __attribute__((ext_vector_type(4)));

// ---------- bf16 helpers ----------
__device__ __forceinline__ float lof(u32 u) { u32 x = u << 16; float f; __builtin_memcpy(&f, &x, 4); return f; }
__device__ __forceinline__ float hif(u32 u) { u32 x = u & 0xffff0000u; float f; __builtin_memcpy(&f, &x, 4); return f; }
__device__ __forceinline__ u16 f2bf(float f) {
  u32 u; __builtin_memcpy(&u, &f, 4);
  u32 r = u + 0x7fffu + ((u >> 16) & 1u);
  return (u16)(r >> 16);
}
__device__ __forceinline__ u32 pack2(float a, float b) { return (u32)f2bf(a) | ((u32)f2bf(b) << 16); }
__device__ __forceinline__ float bf2f(u16 s) { u32 x = ((u32)s) << 16; float f; __builtin_memcpy(&f, &x, 4); return f; }
__device__ __forceinline__ float elem(const u32* arr, int j) { u32 u = arr[j >> 1]; return (j & 1) ? hif(u) : lof(u); }

__device__ __forceinline__ void gload_lds16(const u16* g, u16* l) {
  __builtin_amdgcn_global_load_lds((const __attribute__((address_space(1))) void*)g,
                                   (__attribute__((address_space(3))) void*)l, 16, 0, 0);
}

// cheap GELU: tanh form via HW exp+rcp, |err| <~ 1e-3 absolute.
__device__ __forceinline__ float gelu_f(float x) {
  float x3 = x * x * x;
  float u = fmaf(x3, 0.07135481283f, 1.5957691216f * x);
  float e = __expf(u);
  float r = __builtin_amdgcn_rcpf(e + 1.0f);
  return x * e * r;
}

// ---------- problem constants ----------
#define NTOK 65536      // B*C*P = 8*64*128

// bf16 weight elem offsets inside O_WB
#define WB_PA   0         // proj_attn_w 512x512
#define WB_PF   262144    // proj_ffn_w  512x512 (also packed into W2F)
#define WB_QS   524288    // qkv_s_w*ln1w 768x256
#define WB_QT   720896    // qkv_t_w*ln1w 768x256
#define WB_OS   917504    // out_s_w     256x256
#define WB_OT   983040    // out_t_w     256x256
#define WB_W1   1048576   // w1*ln2w     2048x512
#define WB_W2F  2097152   // [w2 | proj_ffn_w] 512x2560
#define WB_TOT  3407872

// uc float offsets
#define UC_US 0
#define UC_CS 768
#define UC_UT 1536
#define UC_CT 2304
#define UC_U1 3072
#define UC_C1 5120
#define UC_BC 7168

// ws layout (bytes)
constexpr size_t O_WB  = 0;
constexpr size_t O_TAB = 6815744;
constexpr size_t O_ST1 = 6864896;
constexpr size_t O_ST2 = 7389184;
constexpr size_t O_UC  = 7913472;
constexpr size_t O_X   = 7944192;
constexpr size_t O_HB  = O_X + (size_t)NTOK * 512 * 2;

// ---------- weight conversion (with LN folds + fused w2) ----------
__global__ __launch_bounds__(256) void convert_weights_kernel(
    const float* __restrict__ pa, const float* __restrict__ pf,
    const float* __restrict__ qs, const float* __restrict__ qt,
    const float* __restrict__ os_, const float* __restrict__ ot,
    const float* __restrict__ w1, const float* __restrict__ w2,
    const float* __restrict__ ln1w, const float* __restrict__ ln2w,
    u16* __restrict__ dst)
{
  int i = blockIdx.x * 256 + threadIdx.x;
  if (i >= WB_TOT) return;
  float v;
  if (i < 262144)       { v = pa[i]; }
  else if (i < 524288)  { v = pf[i - 262144]; }
  else if (i < 720896)  { int l = i - 524288;  v = qs[l] * ln1w[l & 255]; }
  else if (i < 917504)  { int l = i - 720896;  v = qt[l] * ln1w[256 + (l & 255)]; }
  else if (i < 983040)  { v = os_[i - 917504]; }
  else if (i < 1048576) { v = ot[i - 983040]; }
  else if (i < 2097152) { int l = i - 1048576; v = w1[l] * ln2w[l & 511]; }
  else {
    int l = i - 2097152; int row = l / 2560, col = l - row * 2560;
    v = (col < 2048) ? w2[row * 2048 + col] : pf[row * 512 + (col - 2048)];
  }
  dst[i] = f2bf(v);
}

// ---------- u/c correction vectors + combined bias (wave-parallel) ----------
__global__ __launch_bounds__(256) void ucvec_kernel(
    const float* __restrict__ qs, const float* __restrict__ qt, const float* __restrict__ w1,
    const float* __restrict__ ln1w, const float* __restrict__ ln1b,
    const float* __restrict__ ln2w, const float* __restrict__ ln2b,
    const float* __restrict__ b2, const float* __restrict__ pfb,
    float* __restrict__ uc)
{
  const int j = blockIdx.x * 4 + (threadIdx.x >> 6);
  const int l = threadIdx.x & 63;
  float u = 0.f, c = 0.f;
  if (j < 768) {
#pragma unroll
    for (int q = 0; q < 4; q++) {
      int k = l * 4 + q;
      float w = qs[j * 256 + k];
      u += ln1w[k] * w; c += ln1b[k] * w;
    }
  } else if (j < 1536) {
    int jj = j - 768;
#pragma unroll
    for (int q = 0; q < 4; q++) {
      int k = l * 4 + q;
      float w = qt[jj * 256 + k];
      u += ln1w[256 + k] * w; c += ln1b[256 + k] * w;
    }
  } else if (j < 3584) {
    int jj = j - 1536;
#pragma unroll
    for (int q = 0; q < 8; q++) {
      int k = l * 8 + q;
      float w = w1[jj * 512 + k];
      u += ln2w[k] * w; c += ln2b[k] * w;
    }
  } else if (j < 4096) {
    if (l == 0) { int jj = j - 3584; uc[UC_BC + jj] = b2[jj] + pfb[jj]; }
    return;
  } else return;
#pragma unroll
  for (int o = 32; o > 0; o >>= 1) { u += __shfl_xor(u, o); c += __shfl_xor(c, o); }
  if (l == 0) {
    if (j < 768)       { uc[UC_US + j] = u;          uc[UC_CS + j] = c; }
    else if (j < 1536) { uc[UC_UT + (j - 768)] = u;  uc[UC_CT + (j - 768)] = c; }
    else               { uc[UC_U1 + (j - 1536)] = u; uc[UC_C1 + (j - 1536)] = c; }
  }
}

// ---------- rope tables ----------
__global__ __launch_bounds__(256) void rope_tables_kernel(const float* __restrict__ coords, float* __restrict__ tab)
{
  __shared__ float cs[192];
  __shared__ float mean3[3];
  __shared__ float rmax;
  int t = threadIdx.x;
  if (t < 192) cs[t] = coords[t];
  __syncthreads();
  if (t < 3) { float s = 0.f; for (int i = 0; i < 64; i++) s += cs[i * 3 + t]; mean3[t] = s * (1.0f / 64.0f); }
  __syncthreads();
  if (t < 192) cs[t] -= mean3[t % 3];
  __syncthreads();
  if (t == 0) {
    float mx = 0.f;
    for (int i = 0; i < 64; i++) {
      float x = cs[i * 3], y = cs[i * 3 + 1], z = cs[i * 3 + 2];
      mx = fmaxf(mx, sqrtf(x * x + y * y + z * z));
    }
    rmax = fmaxf(mx, 1e-6f);
  }
  __syncthreads();
  float inv = 1.0f / rmax;
  for (int e = t; e < 2048; e += 256) {
    int c = e >> 5, j = e & 31;
    float freq = 1.0f / powf(10000.0f, (float)j * (1.0f / 32.0f));
    float th = 6.283185307179586f * (cs[c * 3 + (j % 3)] * inv) * freq;
    tab[e] = cosf(th); tab[2048 + e] = sinf(th);
  }
  for (int e = t; e < 4096; e += 256) {
    int p = e >> 5, j = e & 31;
    float freq = 1.0f / powf(10000.0f, (float)j * (1.0f / 32.0f));
    float th = (float)p * freq;
    tab[4096 + e] = cosf(th); tab[8192 + e] = sinf(th);
  }
}

// ---------- LN stats (mean, rstd) per token; optional bf16 cast of src ----------
__global__ __launch_bounds__(256) void ln_stats_f32_kernel(
    const float* __restrict__ xin, float2* __restrict__ st, u16* __restrict__ srcb)
{
  const int tok = blockIdx.x * 4 + (threadIdx.x >> 6);
  const int lane = threadIdx.x & 63;
  const float* row = xin + (size_t)tok * 512 + lane * 8;
  float4 v0 = ((const float4*)row)[0];
  float4 v1 = ((const float4*)row)[1];
  float v[8] = {v0.x, v0.y, v0.z, v0.w, v1.x, v1.y, v1.z, v1.w};
  float s = 0.f, ss = 0.f;
#pragma unroll
  for (int j = 0; j < 8; j++) { s += v[j]; ss += v[j] * v[j]; }
#pragma unroll
  for (int o = 32; o > 0; o >>= 1) { s += __shfl_xor(s, o); ss += __shfl_xor(ss, o); }
  if (lane == 0) {
    float mean = s * (1.0f / 512.0f);
    float rstd = rsqrtf(ss * (1.0f / 512.0f) - mean * mean + 1e-5f);
    st[tok] = make_float2(mean, rstd);
  }
  if (srcb) {
    uint4 o; u32* op = (u32*)&o;
#pragma unroll
    for (int d = 0; d < 4; d++) op[d] = pack2(v[2 * d], v[2 * d + 1]);
    *(uint4*)(srcb + (size_t)tok * 512 + lane * 8) = o;
  }
}

__global__ __launch_bounds__(256) void ln_stats_bf16_kernel(const u16* __restrict__ xin, float2* __restrict__ st)
{
  const int tok = blockIdx.x * 4 + (threadIdx.x >> 6);
  const int lane = threadIdx.x & 63;
  uint4 u = ((const uint4*)(xin + (size_t)tok * 512))[lane];
  u32 uu[4] = {u.x, u.y, u.z, u.w};
  float s = 0.f, ss = 0.f;
#pragma unroll
  for (int d = 0; d < 4; d++) {
    float a = lof(uu[d]), b = hif(uu[d]);
    s += a + b; ss += a * a + b * b;
  }
#pragma unroll
  for (int o = 32; o > 0; o >>= 1) { s += __shfl_xor(s, o); ss += __shfl_xor(ss, o); }
  if (lane == 0) {
    float mean = s * (1.0f / 512.0f);
    float rstd = rsqrtf(ss * (1.0f / 512.0f) - mean * mean + 1e-5f);
    st[tok] = make_float2(mean, rstd);
  }
}

// ---------- 128x128-tile, BK=32, 4-buffer, 2-tile WINDOW pipeline (small GEMMs) ----------
// EMODE: 0 = +bias; 2 = +bias+RMW; 3 = affine(stats,u,c)+bias
template<int EMODE, typename OutT>
__global__ __launch_bounds__(256) void gemm128w_kernel(
    const u16* __restrict__ A16, int lda,
    const u16* __restrict__ Wt, int ldw,
    OutT* __restrict__ C, int ldc,
    const float* __restrict__ bias,
    const float2* __restrict__ stats,
    const float* __restrict__ uvec, const float* __restrict__ cvec,
    int K)
{
  __shared__ u16 As[4][128 * 32];
  __shared__ u16 Bs[4][128 * 32];
  const int t = threadIdx.x;
  const int lane = t & 63, wid = t >> 6;
  const int wm = wid >> 1, wn = wid & 1;
  const int l15 = lane & 15, l4 = lane >> 4;
  const int chs = (t & 3) ^ ((t >> 3) & 3);

  const int ntn = gridDim.x;
  const int nwg = ntn * gridDim.y;
  int flat = blockIdx.y * ntn + blockIdx.x;
  int q = nwg >> 3, rmd = nwg & 7, xcd = flat & 7, idx = flat >> 3;
  int wg = (xcd < rmd ? xcd * (q + 1) : rmd * (q + 1) + (xcd - rmd) * q) + idx;
  const int m0 = (wg / ntn) * 128, n0 = (wg % ntn) * 128;

  f32x4 acc[4][4] = {};
  const int r0 = t >> 2;
  const size_t arow0 = (size_t)(m0 + r0);
  const u16* Wp = Wt + (size_t)(n0 + r0) * ldw + chs * 8;
  const size_t wstep = (size_t)64 * ldw;
  const int nt = K / 32;   // even for all K used (256, 512)

  auto stage = [&](int ti, int buf) {
    const int kk = ti * 32;
    const u16* pa = A16 + arow0 * lda + kk + chs * 8;
    const size_t rstep = (size_t)64 * lda;
    gload_lds16(pa, &As[buf][t * 8]);
    gload_lds16(pa + rstep, &As[buf][t * 8 + 2048]);
    gload_lds16(Wp + kk, &Bs[buf][t * 8]);
    gload_lds16(Wp + wstep + kk, &Bs[buf][t * 8 + 2048]);
  };

  stage(0, 0);
  stage(1, 1);
  const int pco = (l4 ^ ((l15 >> 1) & 3)) * 8;
  for (int p = 0; p < nt; p += 2) {
    __builtin_amdgcn_sched_barrier(0);
    asm volatile("s_waitcnt vmcnt(0)" ::: "memory");
    __builtin_amdgcn_sched_barrier(0);
    __builtin_amdgcn_s_barrier();
    __builtin_amdgcn_sched_barrier(0);
    if (p + 2 < nt) stage(p + 2, (p + 2) & 3);
    if (p + 3 < nt) stage(p + 3, (p + 3) & 3);
#pragma unroll
    for (int s = 0; s < 2; s++) {
      const u16* Ab = &As[(p + s) & 3][0];
      const u16* Bb = &Bs[(p + s) & 3][0];
      bf16x8 af[4], bfr[4];
#pragma unroll
      for (int i = 0; i < 4; i++)
        af[i] = *(const bf16x8*)(Ab + (wm * 64 + i * 16 + l15) * 32 + pco);
#pragma unroll
      for (int j = 0; j < 4; j++)
        bfr[j] = *(const bf16x8*)(Bb + (wn * 64 + j * 16 + l15) * 32 + pco);
#pragma unroll
      for (int i = 0; i < 4; i++)
#pragma unroll
        for (int j = 0; j < 4; j++)
          acc[i][j] = __builtin_amdgcn_mfma_f32_16x16x32_bf16(af[i], bfr[j], acc[i][j], 0, 0, 0);
    }
    __builtin_amdgcn_sched_barrier(0);
  }

#pragma unroll
  for (int i = 0; i < 4; i++) {
    const int row = m0 + wm * 64 + i * 16 + l4 * 4;
#pragma unroll
    for (int j = 0; j < 4; j++) {
      const int col = n0 + wn * 64 + j * 16 + l15;
      const float bv = bias[col];
#pragma unroll
      for (int rr = 0; rr < 4; rr++) {
        float v = acc[i][j][rr];
        if constexpr (EMODE == 3) {
          float2 s = stats[row + rr];
          v = s.y * v - s.x * s.y * uvec[col] + cvec[col] + bv;
        } else {
          v += bv;
        }
        const size_t idxc = (size_t)(row + rr) * ldc + col;
        if constexpr (std::is_same<OutT, u16>::value) {
          if constexpr (EMODE == 2) v += bf2f(C[idxc]);
          C[idxc] = f2bf(v);
        } else {
          if constexpr (EMODE == 2) v += C[idxc];
          C[idxc] = v;
        }
      }
    }
  }
}

// ---------- 256x256-tile, BK=32, 4-buffer, 2-tile WINDOW pipeline (FFN; best=r17) ----------
// AMODE: 0 = single bf16 A; 4 = dual A (k<2048 -> A16 else A2; boundary tile-aligned)
// EMODE: 0 = +bias; 4 = gelu(affine(stats,u,c)+bias)
template<int AMODE, int EMODE, typename OutT>
__global__ __launch_bounds__(512, 2) void gemm2w_kernel(
    const u16* __restrict__ A16, int lda,
    const u16* __restrict__ A2, int lda2,
    const u16* __restrict__ Wt, int ldw,
    OutT* __restrict__ C, int ldc,
    const float* __restrict__ bias,
    const float2* __restrict__ stats,
    const float* __restrict__ uvec, const float* __restrict__ cvec,
    int K)
{
  __shared__ u16 As[4][256 * 32];
  __shared__ u16 Bs[4][256 * 32];
  const int t = threadIdx.x;
  const int lane = t & 63, wid = t >> 6;
  const int wm = wid >> 2, wn = wid & 3;
  const int l15 = lane & 15, l4 = lane >> 4;
  const int r0 = t >> 2;
  const int chs = (t & 3) ^ ((t >> 3) & 3);

  const int ntn = gridDim.x;
  const int nwg = ntn * gridDim.y;
  int flat = blockIdx.y * ntn + blockIdx.x;
  int q = nwg >> 3, rmd = nwg & 7, xcd = flat & 7, idx = flat >> 3;
  int wg = (xcd < rmd ? xcd * (q + 1) : rmd * (q + 1) + (xcd - rmd) * q) + idx;
  const int m0 = (wg / ntn) * 256, n0 = (wg % ntn) * 256;

  f32x4 acc[8][4] = {};

  const size_t arow0 = (size_t)(m0 + r0);
  const u16* Wp = Wt + (size_t)(n0 + r0) * ldw + chs * 8;
  const size_t wstep = (size_t)128 * ldw;
  const int nt = K >> 5;   // even for all our K (512, 2560)

  auto stage = [&](int ti, int buf) {
    const int kk = ti << 5;
    const int cbk = kk + chs * 8;
    const u16* pa; size_t rstep;
    if constexpr (AMODE == 4) {
      if (kk < 2048) { pa = A16 + arow0 * lda + cbk;          rstep = (size_t)128 * lda; }
      else           { pa = A2 + arow0 * lda2 + (cbk - 2048); rstep = (size_t)128 * lda2; }
    } else {
      pa = A16 + arow0 * lda + cbk; rstep = (size_t)128 * lda;
    }
    gload_lds16(pa,         &As[buf][t * 8]);
    gload_lds16(pa + rstep, &As[buf][t * 8 + 4096]);
    gload_lds16(Wp + kk,          &Bs[buf][t * 8]);
    gload_lds16(Wp + wstep + kk,  &Bs[buf][t * 8 + 4096]);
  };

  stage(0, 0);
  stage(1, 1);
  const int pco = (l4 ^ ((l15 >> 1) & 3)) * 8;
  for (int p = 0; p < nt; p += 2) {
    __builtin_amdgcn_sched_barrier(0);
    asm volatile("s_waitcnt vmcnt(0)" ::: "memory");
    __builtin_amdgcn_sched_barrier(0);
    __builtin_amdgcn_s_barrier();
    __builtin_amdgcn_sched_barrier(0);
    if (p + 2 < nt) stage(p + 2, (p + 2) & 3);
    if (p + 3 < nt) stage(p + 3, (p + 3) & 3);
#pragma unroll
    for (int s = 0; s < 2; s++) {
      const u16* Ab = &As[(p + s) & 3][0];
      const u16* Bb = &Bs[(p + s) & 3][0];
      bf16x8 af[8], bfr[4];
#pragma unroll
      for (int i = 0; i < 8; i++)
        af[i] = *(const bf16x8*)(Ab + (wm * 128 + i * 16 + l15) * 32 + pco);
#pragma unroll
      for (int j = 0; j < 4; j++)
        bfr[j] = *(const bf16x8*)(Bb + (wn * 64 + j * 16 + l15) * 32 + pco);
      __builtin_amdgcn_s_setprio(1);
#pragma unroll
      for (int i = 0; i < 8; i++)
#pragma unroll
        for (int j = 0; j < 4; j++)
          acc[i][j] = __builtin_amdgcn_mfma_f32_16x16x32_bf16(af[i], bfr[j], acc[i][j], 0, 0, 0);
      __builtin_amdgcn_s_setprio(0);
    }
    __builtin_amdgcn_sched_barrier(0);
  }

#pragma unroll
  for (int i = 0; i < 8; i++) {
    const int row = m0 + wm * 128 + i * 16 + l4 * 4;
#pragma unroll
    for (int j = 0; j < 4; j++) {
      const int col = n0 + wn * 64 + j * 16 + l15;
      const float bv = bias[col];
#pragma unroll
      for (int rr = 0; rr < 4; rr++) {
        float v = acc[i][j][rr];
        if constexpr (EMODE == 4) {
          float2 s = stats[row + rr];
          v = s.y * v - s.x * s.y * uvec[col] + cvec[col] + bv;
          v = gelu_f(v);
        } else {
          v += bv;
        }
        const size_t idxc = (size_t)(row + rr) * ldc + col;
        if constexpr (std::is_same<OutT, u16>::value) C[idxc] = f2bf(v);
        else C[idxc] = v;
      }
    }
  }
}

// ---------- legacy 128x128 kernel (f32 reg-staged A; fallback when ws too small) ----------
template<int EMODE, typename OutT>
__global__ __launch_bounds__(256) void gemm_f32a_kernel(
    const float* __restrict__ A32, int lda,
    const u16* __restrict__ Wt, int ldw,
    OutT* __restrict__ C, int ldc,
    const float* __restrict__ bias,
    const float2* __restrict__ stats,
    const float* __restrict__ uvec, const float* __restrict__ cvec,
    int K)
{
  const int t = threadIdx.x;
  const int lane = t & 63, wid = t >> 6;
  const int wm = wid >> 1, wn = wid & 1;
  const int l15 = lane & 15, l4 = lane >> 4;
  const int r0 = t >> 2;
  const int ntn = gridDim.x;
  const int nwg = ntn * gridDim.y;
  int flat = blockIdx.y * ntn + blockIdx.x;
  int q = nwg >> 3, rmd = nwg & 7, xcd = flat & 7, idx = flat >> 3;
  int wg = (xcd < rmd ? xcd * (q + 1) : rmd * (q + 1) + (xcd - rmd) * q) + idx;
  const int m0 = (wg / ntn) * 128, n0 = (wg % ntn) * 128;
  f32x4 acc[4][4] = {};
  const size_t arow0 = (size_t)(m0 + r0);
  const int ch = t & 3;
  const u16* Wp = Wt + (size_t)(n0 + r0) * ldw + ch * 8;
  const size_t wstep = (size_t)64 * ldw;
  __shared__ u16 As[128 * 40];
  __shared__ u16 Bs[128 * 32];
  for (int k0 = 0; k0 < K; k0 += 32) {
    const int cbx = k0 + ch * 8;
    uint4 a0, a1;
    float f0[8], f1[8];
    float4 x0 = *(const float4*)(A32 + arow0 * lda + cbx);
    float4 x1 = *(const float4*)(A32 + arow0 * lda + cbx + 4);
    float4 y0 = *(const float4*)(A32 + (arow0 + 64) * lda + cbx);
    float4 y1 = *(const float4*)(A32 + (arow0 + 64) * lda + cbx + 4);
    f0[0]=x0.x; f0[1]=x0.y; f0[2]=x0.z; f0[3]=x0.w; f0[4]=x1.x; f0[5]=x1.y; f0[6]=x1.z; f0[7]=x1.w;
    f1[0]=y0.x; f1[1]=y0.y; f1[2]=y0.z; f1[3]=y0.w; f1[4]=y1.x; f1[5]=y1.y; f1[6]=y1.z; f1[7]=y1.w;
    u32* p0 = (u32*)&a0; u32* p1 = (u32*)&a1;
#pragma unroll
    for (int d = 0; d < 4; d++) { p0[d] = pack2(f0[2*d], f0[2*d+1]); p1[d] = pack2(f1[2*d], f1[2*d+1]); }
    __syncthreads();
    gload_lds16(Wp + k0, Bs + t * 8);
    gload_lds16(Wp + wstep + k0, Bs + t * 8 + 2048);
    *(uint4*)(As + r0 * 40 + ch * 8) = a0;
    *(uint4*)(As + (r0 + 64) * 40 + ch * 8) = a1;
    __syncthreads();
    bf16x8 af[4], bfr[4];
#pragma unroll
    for (int i = 0; i < 4; i++)
      af[i] = *(const bf16x8*)(As + (wm * 64 + i * 16 + l15) * 40 + l4 * 8);
#pragma unroll
    for (int j = 0; j < 4; j++)
      bfr[j] = *(const bf16x8*)(Bs + (wn * 64 + j * 16 + l15) * 32 + l4 * 8);
#pragma unroll
    for (int i = 0; i < 4; i++)
#pragma unroll
      for (int j = 0; j < 4; j++)
        acc[i][j] = __builtin_amdgcn_mfma_f32_16x16x32_bf16(af[i], bfr[j], acc[i][j], 0, 0, 0);
  }
#pragma unroll
  for (int i = 0; i < 4; i++) {
    const int row = m0 + wm * 64 + i * 16 + l4 * 4;
#pragma unroll
    for (int j = 0; j < 4; j++) {
      const int col = n0 + wn * 64 + j * 16 + l15;
      const float bv = bias[col];
#pragma unroll
      for (int rr = 0; rr < 4; rr++) {
        float v = acc[i][j][rr];
        if constexpr (EMODE == 3) {
          float2 s = stats[row + rr];
          v = s.y * v - s.x * s.y * uvec[col] + cvec[col] + bv;
        } else {
          v += bv;
        }
        const size_t idxc = (size_t)(row + rr) * ldc + col;
        if constexpr (std::is_same<OutT, u16>::value) C[idxc] = f2bf(v);
        else C[idxc] = v;
      }
    }
  }
}

// ---------- MFMA fused attention: rope + QK^T + softmax + PV ----------
template<int L>
__global__ __launch_bounds__(256) void attn_mfma_kernel(
    const u16* __restrict__ qkv,   // [NTOK][768]
    u16* __restrict__ aout,        // [NTOK][256]
    const float* __restrict__ tab)
{
  constexpr int KP = 72;
  constexpr int PP = L + 8;
  constexpr int VP = L + 8;
  constexpr int NI = L / 64;
  constexpr int NJ = L / 16;
  constexpr int NK = L / 32;
  __shared__ u16 Ks[L * KP];
  __shared__ u16 Vt[64 * VP];
  __shared__ u16 Ps[L * PP];

  const int t = threadIdx.x;
  const int lane = t & 63;
  const int w = t >> 6;
  const int l15 = lane & 15, l4 = lane >> 4;
  const int sq = blockIdx.x, h = blockIdx.y;

  long base; int tstride; const float *ct, *st;
  if constexpr (L == 64) { base = (long)(sq >> 7) * 8192 + (sq & 127); tstride = 128; ct = tab;        st = tab + 2048; }
  else                   { base = (long)sq * 128;                      tstride = 1;   ct = tab + 4096; st = tab + 8192; }

  {
    const int tok = t >> 1, hh = t & 1;
    if (tok < L) {
      const size_t rb = (size_t)(base + (long)tok * tstride) * 768 + h * 64;
      u32 ku[32];
#pragma unroll
      for (int i = 0; i < 8; i++) ((uint4*)ku)[i] = ((const uint4*)(qkv + rb + 256))[i];
      const float* cc = ct + tok * 32;
      const float* ss = st + tok * 32;
      u32* kd = (u32*)(Ks + tok * KP + hh * 32);
#pragma unroll
      for (int jj = 0; jj < 16; jj++) {
        float c0 = cc[2*jj], s0 = ss[2*jj], c1 = cc[2*jj+1], s1 = ss[2*jj+1];
        float a0 = elem(ku, 2*jj),     b0 = elem(ku, 2*jj+32);
        float a1 = elem(ku, 2*jj+1),   b1 = elem(ku, 2*jj+33);
        float r0v = hh ? (a0*s0 + b0*c0) : (a0*c0 - b0*s0);
        float r1v = hh ? (a1*s1 + b1*c1) : (a1*c1 - b1*s1);
        kd[jj] = pack2(r0v, r1v);
      }
      u32 vu[16];
#pragma unroll
      for (int i = 0; i < 4; i++) ((uint4*)vu)[i] = ((const uint4*)(qkv + rb + 512 + hh * 32))[i];
#pragma unroll
      for (int j = 0; j < 32; j++)
        Vt[(hh * 32 + j) * VP + tok] = (u16)(vu[j >> 1] >> ((j & 1) * 16));
    }
  }

  bf16x8 aq[NI][2];
#pragma unroll
  for (int i = 0; i < NI; i++) {
    const int row = w * (16 * NI) + i * 16 + l15;
    const u16* qr = qkv + (size_t)(base + (long)row * tstride) * 768 + h * 64;
    uint4 ua = *(const uint4*)(qr + l4 * 8);
    uint4 ub = *(const uint4*)(qr + 32 + l4 * 8);
    u32 au[4] = {ua.x, ua.y, ua.z, ua.w};
    u32 bu[4] = {ub.x, ub.y, ub.z, ub.w};
    const float* cc = ct + row * 32 + l4 * 8;
    const float* ss = st + row * 32 + l4 * 8;
    u32 q0[4], q1[4];
#pragma unroll
    for (int d = 0; d < 4; d++) {
      float a0 = lof(au[d]), a1 = hif(au[d]);
      float b0 = lof(bu[d]), b1 = hif(bu[d]);
      float c0 = cc[2*d], c1 = cc[2*d+1], s0 = ss[2*d], s1 = ss[2*d+1];
      q0[d] = pack2(a0*c0 - b0*s0, a1*c1 - b1*s1);
      q1[d] = pack2(a0*s0 + b0*c0, a1*s1 + b1*c1);
    }
    __builtin_memcpy(&aq[i][0], q0, 16);
    __builtin_memcpy(&aq[i][1], q1, 16);
  }
  __syncthreads();

  f32x4 acc[NI][NJ] = {};
#pragma unroll
  for (int j = 0; j < NJ; j++) {
#pragma unroll
    for (int kk = 0; kk < 2; kk++) {
      bf16x8 bk = *(const bf16x8*)(Ks + (j * 16 + l15) * KP + kk * 32 + l4 * 8);
#pragma unroll
      for (int i = 0; i < NI; i++)
        acc[i][j] = __builtin_amdgcn_mfma_f32_16x16x32_bf16(aq[i][kk], bk, acc[i][j], 0, 0, 0);
    }
  }

  float inv_[NI][4];
#pragma unroll
  for (int i = 0; i < NI; i++) {
#pragma unroll
    for (int rr = 0; rr < 4; rr++) {
      float m = acc[i][0][rr];
#pragma unroll
      for (int j = 1; j < NJ; j++) m = fmaxf(m, acc[i][j][rr]);
      m = fmaxf(m, __shfl_xor(m, 1)); m = fmaxf(m, __shfl_xor(m, 2));
      m = fmaxf(m, __shfl_xor(m, 4)); m = fmaxf(m, __shfl_xor(m, 8));
      m *= 0.125f;
      const int qrow = w * (16 * NI) + i * 16 + l4 * 4 + rr;
      float sm = 0.f;
#pragma unroll
      for (int j = 0; j < NJ; j++) {
        float e = __expf(acc[i][j][rr] * 0.125f - m);
        sm += e;
        Ps[qrow * PP + j * 16 + l15] = f2bf(e);
      }
      sm += __shfl_xor(sm, 1); sm += __shfl_xor(sm, 2);
      sm += __shfl_xor(sm, 4); sm += __shfl_xor(sm, 8);
      inv_[i][rr] = 1.0f / sm;
    }
  }

  f32x4 o[NI][4] = {};
#pragma unroll
  for (int kk = 0; kk < NK; kk++) {
    bf16x8 pa[NI];
#pragma unroll
    for (int i = 0; i < NI; i++)
      pa[i] = *(const bf16x8*)(Ps + (w * (16 * NI) + i * 16 + l15) * PP + kk * 32 + l4 * 8);
#pragma unroll
    for (int jn = 0; jn < 4; jn++) {
      bf16x8 bv = *(const bf16x8*)(Vt + (jn * 16 + l15) * VP + kk * 32 + l4 * 8);
#pragma unroll
      for (int i = 0; i < NI; i++)
        o[i][jn] = __builtin_amdgcn_mfma_f32_16x16x32_bf16(pa[i], bv, o[i][jn], 0, 0, 0);
    }
  }

#pragma unroll
  for (int i = 0; i < NI; i++) {
#pragma unroll
    for (int rr = 0; rr < 4; rr++) {
      const int qrow = w * (16 * NI) + i * 16 + l4 * 4 + rr;
      u16* op = aout + (size_t)(base + (long)qrow * tstride) * 256 + h * 64;
      const float iv = inv_[i][rr];
#pragma unroll
      for (int jn = 0; jn < 4; jn++)
        op[jn * 16 + l15] = f2bf(o[i][jn][rr] * iv);
    }
  }
}

// ---------- launch ----------
extern "C" void kernel_launch(void* const* d_in, const int* in_sizes, int n_in,
                              void* d_out, int out_size, void* d_ws, size_t ws_size,
                              hipStream_t stream) {
  const float* src         = (const float*)d_in[0];
  const float* coords      = (const float*)d_in[1];
  const float* proj_attn_w = (const float*)d_in[4];
  const float* proj_attn_b = (const float*)d_in[5];
  const float* proj_ffn_w  = (const float*)d_in[8];
  const float* proj_ffn_b  = (const float*)d_in[9];
  const float* ln1_w = (const float*)d_in[10];
  const float* ln1_b = (const float*)d_in[11];
  const float* ln2_w = (const float*)d_in[12];
  const float* ln2_b = (const float*)d_in[13];
  const float* qkv_s_w = (const float*)d_in[14];
  const float* qkv_s_b = (const float*)d_in[15];
  const float* out_s_w = (const float*)d_in[16];
  const float* out_s_b = (const float*)d_in[17];
  const float* qkv_t_w = (const float*)d_in[18];
  const float* qkv_t_b = (const float*)d_in[19];
  const float* out_t_w = (const float*)d_in[20];
  const float* out_t_b = (const float*)d_in[21];
  const float* w1 = (const float*)d_in[22];
  const float* b1 = (const float*)d_in[23];
  const float* w2 = (const float*)d_in[24];
  const float* b2 = (const float*)d_in[25];
  float* out = (float*)d_out;
  char* ws = (char*)d_ws;

  // FFN chunk: 32768 rows -> hb chunk = 134MB, L3-resident between w1-write and
  // w2-read; w2 grid = 256 blocks (1/CU, full chip).
  const size_t srcb_bytes = (size_t)NTOK * 512 * 2;
  const int tiers[6] = {32768, 16384, 8192, 4096, 2048, 512};
  int crows = 0; bool fast = false;
  for (int i = 0; i < 6; i++) {
    size_t need = O_HB + (size_t)tiers[i] * 2048 * 2 + srcb_bytes;
    if (ws_size >= need) { crows = tiers[i]; fast = true; break; }
  }
  if (!crows) {
    for (int i = 0; i < 6; i++)
      if (ws_size >= O_HB + (size_t)tiers[i] * 2048 * 2) { crows = tiers[i]; break; }
  }
  if (!crows) return;
  size_t o_srcb = O_HB + (size_t)crows * 2048 * 2;

  u16*    wb  = (u16*)(ws + O_WB);
  float*  tab = (float*)(ws + O_TAB);
  float2* st1 = (float2*)(ws + O_ST1);
  float2* st2 = (float2*)(ws + O_ST2);
  float*  uc  = (float*)(ws + O_UC);
  u16*    x   = (u16*)(ws + O_X);
  u16*    hb  = (u16*)(ws + O_HB);
  u16*    srcb = fast ? (u16*)(ws + o_srcb) : nullptr;

  u16* qkvb  = (u16*)d_out;
  u16* aoutb = (u16*)((char*)d_out + (size_t)NTOK * 768 * 2);

  convert_weights_kernel<<<(WB_TOT + 255) / 256, 256, 0, stream>>>(
      proj_attn_w, proj_ffn_w, qkv_s_w, qkv_t_w, out_s_w, out_t_w, w1, w2, ln1_w, ln2_w, wb);
  ucvec_kernel<<<1024, 256, 0, stream>>>(qkv_s_w, qkv_t_w, w1, ln1_w, ln1_b, ln2_w, ln2_b, b2, proj_ffn_b, uc);
  rope_tables_kernel<<<1, 256, 0, stream>>>(coords, tab);
  ln_stats_f32_kernel<<<NTOK / 4, 256, 0, stream>>>(src, st1, srcb);

  // res1 = src @ proj_attn_w^T + b -> x
  if (fast)
    gemm128w_kernel<0, u16><<<dim3(4, 512), 256, 0, stream>>>(srcb, 512, wb + WB_PA, 512, x, 512, proj_attn_b, nullptr, nullptr, nullptr, 512);
  else
    gemm_f32a_kernel<0, u16><<<dim3(4, 512), 256, 0, stream>>>(src, 512, wb + WB_PA, 512, x, 512, proj_attn_b, nullptr, nullptr, nullptr, 512);

  // spatial attention: qkv on raw src with LN folded into weights + affine epilogue
  if (fast)
    gemm128w_kernel<3, u16><<<dim3(6, 512), 256, 0, stream>>>(srcb, 512, wb + WB_QS, 256, qkvb, 768, qkv_s_b, st1, uc + UC_US, uc + UC_CS, 256);
  else
    gemm_f32a_kernel<3, u16><<<dim3(6, 512), 256, 0, stream>>>(src, 512, wb + WB_QS, 256, qkvb, 768, qkv_s_b, st1, uc + UC_US, uc + UC_CS, 256);
  attn_mfma_kernel<64><<<dim3(1024, 4), 256, 0, stream>>>(qkvb, aoutb, tab);
  gemm128w_kernel<2, u16><<<dim3(2, 512), 256, 0, stream>>>(aoutb, 256, wb + WB_OS, 256, x, 512, out_s_b, nullptr, nullptr, nullptr, 256);

  // temporal attention
  if (fast)
    gemm128w_kernel<3, u16><<<dim3(6, 512), 256, 0, stream>>>(srcb + 256, 512, wb + WB_QT, 256, qkvb, 768, qkv_t_b, st1, uc + UC_UT, uc + UC_CT, 256);
  else
    gemm_f32a_kernel<3, u16><<<dim3(6, 512), 256, 0, stream>>>(src + 256, 512, wb + WB_QT, 256, qkvb, 768, qkv_t_b, st1, uc + UC_UT, uc + UC_CT, 256);
  attn_mfma_kernel<128><<<dim3(512, 4), 256, 0, stream>>>(qkvb, aoutb, tab);
  gemm128w_kernel<2, u16><<<dim3(2, 512), 256, 0, stream>>>(aoutb, 256, wb + WB_OT, 256, x + 256, 512, out_t_b, nullptr, nullptr, nullptr, 256);

  // LN2 stats over x (raw x kept; LN2 folded into w1 weights)
  ln_stats_bf16_kernel<<<NTOK / 4, 256, 0, stream>>>(x, st2);

  // FFN chunks: hb = gelu(affine(x @ W1')); out = hb @ w2^T + x @ proj_ffn^T + (b2 + pfb)
  for (int r = 0; r < NTOK; r += crows) {
    gemm2w_kernel<0, 4, u16><<<dim3(8, crows / 256), 512, 0, stream>>>(
        x + (size_t)r * 512, 512, nullptr, 0, wb + WB_W1, 512, hb, 2048, b1, st2 + r, uc + UC_U1, uc + UC_C1, 512);
    gemm2w_kernel<4, 0, float><<<dim3(2, crows / 256), 512, 0, stream>>>(
        hb, 2048, x + (size_t)r * 512, 512, wb + WB_W2F, 2560, out + (size_t)r * 512, 512, uc + UC_BC, nullptr, nullptr, nullptr, 2560);
  }
}